// Round 18
// baseline (243.616 us; speedup 1.0000x reference)
//
#include <hip/hip_runtime.h>
#include <stdint.h>

#define D_MODEL 2048
#define N_HEAD 32
#define N_KV_HEAD 8
#define HEAD_DIM 64
#define BATCH 2
#define SEQ 2048
#define ROWS (BATCH*SEQ)   // 4096
#define QKV_N 3072         // fused projection width: Q 0..2047 | K 2048..2559 | V 2560..3071
#define SCL2F 0.18033688011112042f   // 0.125 * log2(e)

typedef __attribute__((ext_vector_type(4))) float f32x4;
typedef __attribute__((ext_vector_type(8))) short bf16x8;

__device__ __forceinline__ float bflo(unsigned u){ return __uint_as_float(u << 16); }
__device__ __forceinline__ float bfhi(unsigned u){ return __uint_as_float(u & 0xFFFF0000u); }
__device__ __forceinline__ unsigned f2bf(float f){
  unsigned u = __float_as_uint(f);
  u += 0x7FFFu + ((u >> 16) & 1u);
  return u >> 16;   // RNE bf16 in low 16 bits
}
__device__ __forceinline__ unsigned cvtpk(float a, float b){
  unsigned r;
  asm("v_cvt_pk_bf16_f32 %0, %1, %2" : "=v"(r) : "v"(a), "v"(b));
  return r;
}

__device__ __forceinline__ void async_copy16(const void* g, void* lds){
  __builtin_amdgcn_global_load_lds(
      (const __attribute__((address_space(1))) void*)g,
      (__attribute__((address_space(3))) void*)lds, 16, 0, 0);
}

// ---------------- fused prep: fp32->bf16 cvt | 4 weight transposes | RoPE tables ----------------
__global__ __launch_bounds__(256) void k_prep(const float* __restrict__ x,
                                              const float* __restrict__ Wq,
                                              const float* __restrict__ Wk,
                                              const float* __restrict__ Wv,
                                              const float* __restrict__ Wo,
                                              unsigned short* __restrict__ xb,
                                              unsigned short* __restrict__ Wqkvt,
                                              unsigned short* __restrict__ Wot,
                                              float* __restrict__ ct,
                                              float* __restrict__ st){
  __shared__ float tile[64][65];
  const int bid = blockIdx.x;
  const int tid = threadIdx.x;
  if (bid < 8192) {
    int i = bid*256 + tid;
    float4 v = ((const float4*)x)[i];
    unsigned lo = f2bf(v.x) | (f2bf(v.y) << 16);
    unsigned hi = f2bf(v.z) | (f2bf(v.w) << 16);
    ((uint2*)xb)[i] = make_uint2(lo, hi);
    return;
  }
  if (bid < 10752) {
    const int rel0 = bid - 8192;
    const float* W; unsigned short* Wt; int N; int rel;
    if (rel0 < 1024)      { W = Wq; Wt = Wqkvt;                         N = 2048; rel = rel0; }
    else if (rel0 < 1280) { W = Wk; Wt = Wqkvt + (size_t)2048*D_MODEL;  N = 512;  rel = rel0 - 1024; }
    else if (rel0 < 1536) { W = Wv; Wt = Wqkvt + (size_t)2560*D_MODEL;  N = 512;  rel = rel0 - 1280; }
    else                  { W = Wo; Wt = Wot;                           N = 2048; rel = rel0 - 1536; }
    const int ntn = N >> 6;
    const int tk = rel / ntn, tn = rel % ntn;
    #pragma unroll
    for (int i = 0; i < 4; ++i) {
      int idx4 = tid + 256*i;
      int r = idx4 >> 4;
      int c4 = idx4 & 15;
      float4 v = *(const float4*)(W + (size_t)(tk*64 + r)*N + tn*64 + c4*4);
      tile[r][c4*4+0] = v.x; tile[r][c4*4+1] = v.y;
      tile[r][c4*4+2] = v.z; tile[r][c4*4+3] = v.w;
    }
    __syncthreads();
    #pragma unroll
    for (int i = 0; i < 8; ++i) {
      int o2 = tid + 256*i;
      int n  = o2 >> 5;
      int k2 = o2 & 31;
      unsigned lo = f2bf(tile[k2*2+0][n]);
      unsigned hi = f2bf(tile[k2*2+1][n]);
      *(unsigned*)(Wt + (size_t)(tn*64 + n)*D_MODEL + tk*64 + k2*2) = lo | (hi << 16);
    }
    return;
  }
  {
    int gid = (bid - 10752)*256 + tid;   // SEQ*32
    int t = gid >> 5, d = gid & 31;
    float inv = exp2f(-13.287712379549449f * ((float)d * (1.0f/32.0f)));
    float a = (float)t * inv;
    ct[gid] = cosf(a);
    st[gid] = sinf(a);
  }
}

// ---------------- RoPE-K in-place (128 blocks); V handled by the GEMM epilogue ----------------
__global__ __launch_bounds__(256) void k_ropek(unsigned short* __restrict__ QKVb,
                                               const float* __restrict__ ct,
                                               const float* __restrict__ st){
  int gid = blockIdx.x*256 + threadIdx.x;   // ROWS*N_KV_HEAD
  int row = gid >> 3;
  int h = gid & 7;
  int t = row & (SEQ-1);
  unsigned* p = (unsigned*)(QKVb + (size_t)row*QKV_N + 2048 + h*HEAD_DIM);
  float o1[32], o2[32];
  #pragma unroll
  for (int d = 0; d < 32; ++d) {
    unsigned u = p[d];
    float x1 = bflo(u), x2 = bfhi(u);
    float c = ct[t*32+d], s = st[t*32+d];
    o1[d] = x1*c - x2*s;
    o2[d] = x1*s + x2*c;
  }
  #pragma unroll
  for (int i = 0; i < 16; ++i) {
    p[i]    = f2bf(o1[2*i]) | (f2bf(o1[2*i+1]) << 16);
    p[16+i] = f2bf(o2[2*i]) | (f2bf(o2[2*i+1]) << 16);
  }
}

// ---------------- 8-phase pipelined bf16 GEMM (T2+T3+T4+T5): C = A[M][K] * Bt[N][K]^T ----------------
// R15-proven schedule. VSPLIT: N-tiles with n0 >= 2560 (pure V in the fused QKV projection)
// write their output TRANSPOSED directly into Vt[(b*8+kvh)*64+d][s].
template<int MREP, bool VSPLIT, typename OUT_T>
__global__ __launch_bounds__(512, 1) void k_gemm8(const unsigned short* __restrict__ A,
                                                  const unsigned short* __restrict__ Bt,
                                                  OUT_T* __restrict__ C,
                                                  unsigned short* __restrict__ Vt,
                                                  int M, int N, int K){
  constexpr int BM = MREP*32;
  constexpr int ABYTES = BM*128;
  constexpr int AHALF  = BM*64;
  constexpr int BUF = ABYTES + 32768;
  constexpr int LA = MREP/4;
  constexpr int VMW = 6 + 2*LA;

  __shared__ __align__(16) char smem[2*BUF];

  const int nbn = N >> 8;
  const int bswz = ((int)blockIdx.x & 7)*((int)gridDim.x >> 3) + ((int)blockIdx.x >> 3);
  const int m0 = (bswz / nbn) * BM;
  const int n0 = (bswz % nbn) * 256;
  const int tid = threadIdx.x;
  const int wid = tid >> 6, lane = tid & 63;
  const int wm = wid >> 2, wn = wid & 3;
  const int fr = lane & 15, q = lane >> 4;
  const int NT = K >> 6;
  const int NITER = NT >> 1;
  const size_t rb = (size_t)K*2;

  f32x4 acc[MREP][4] = {};
  bf16x8 Bfrag[4];

  const int srow = tid >> 2, sq = tid & 3;

  auto stageA = [&](int t, int ks, int bufb){
    #pragma unroll
    for (int r = 0; r < LA; ++r){
      int row = r*128 + srow;
      int sw = ((row >> 1) & 3);
      async_copy16((const char*)A + (size_t)(m0+row)*rb + t*128 + ks*64 + ((sq ^ sw)*16),
                   smem + bufb + ks*AHALF + (r*512 + tid)*16);
    }
  };
  auto stageB = [&](int t, int ks, int bufb){
    #pragma unroll
    for (int r = 0; r < 2; ++r){
      int row = r*128 + srow;
      int sw = ((row >> 1) & 3);
      async_copy16((const char*)Bt + (size_t)(n0+row)*rb + t*128 + ks*64 + ((sq ^ sw)*16),
                   smem + bufb + ABYTES + ks*16384 + (r*512 + tid)*16);
    }
  };

#define PHASE(KS, MH, BUFB, LOADB, STAGE_STMT, DO_VMCNT) {                              \
    bf16x8 Af[MREP/2];                                                                  \
    _Pragma("unroll")                                                                   \
    for (int mm = 0; mm < MREP/2; ++mm){                                                \
      int row = wm*(MREP*16) + ((MH)*(MREP/2)+mm)*16 + fr;                              \
      Af[mm] = *(const bf16x8*)(smem + (BUFB) + (KS)*AHALF + row*64 +                   \
                                ((q ^ ((row>>1)&3))*16));                               \
    }                                                                                   \
    if (LOADB){                                                                         \
      _Pragma("unroll")                                                                 \
      for (int n = 0; n < 4; ++n){                                                      \
        int row = wn*64 + n*16 + fr;                                                    \
        Bfrag[n] = *(const bf16x8*)(smem + (BUFB) + ABYTES + (KS)*16384 + row*64 +      \
                                    ((q ^ ((row>>1)&3))*16));                           \
      }                                                                                 \
    }                                                                                   \
    STAGE_STMT;                                                                         \
    __builtin_amdgcn_s_barrier();                                                       \
    __builtin_amdgcn_s_setprio(1);                                                      \
    _Pragma("unroll")                                                                   \
    for (int mm = 0; mm < MREP/2; ++mm)                                                 \
      _Pragma("unroll")                                                                 \
      for (int n = 0; n < 4; ++n)                                                       \
        acc[(MH)*(MREP/2)+mm][n] = __builtin_amdgcn_mfma_f32_16x16x32_bf16(             \
            Af[mm], Bfrag[n], acc[(MH)*(MREP/2)+mm][n], 0, 0, 0);                       \
    __builtin_amdgcn_s_setprio(0);                                                      \
    if (DO_VMCNT) asm volatile("s_waitcnt vmcnt(%0)" :: "n"(VMW) : "memory");           \
    __builtin_amdgcn_s_barrier();                                                       \
  }

  stageB(0, 0, 0);  stageA(0, 0, 0);  stageB(0, 1, 0);  stageA(0, 1, 0);
  stageB(1, 0, BUF); stageA(1, 0, BUF); stageB(1, 1, BUF);
  asm volatile("s_waitcnt vmcnt(%0)" :: "n"(VMW) : "memory");
  __builtin_amdgcn_s_barrier();

  for (int i = 0; i < NITER; ++i){
    const int t2 = (2*i+2) & (NT-1);
    const int t3 = (2*i+3) & (NT-1);
    PHASE(0, 0, 0,   true,  stageA(2*i+1, 1, BUF), false)
    PHASE(0, 1, 0,   false, stageB(t2, 0, 0),      true)
    PHASE(1, 0, 0,   true,  stageA(t2, 0, 0),      false)
    PHASE(1, 1, 0,   false, stageB(t2, 1, 0),      true)
    PHASE(0, 0, BUF, true,  stageA(t2, 1, 0),      false)
    PHASE(0, 1, BUF, false, stageB(t3, 0, BUF),    true)
    PHASE(1, 0, BUF, true,  stageA(t3, 0, BUF),    false)
    PHASE(1, 1, BUF, false, stageB(t3, 1, BUF),    true)
  }
#undef PHASE

  asm volatile("s_waitcnt vmcnt(0)" ::: "memory");
  const bool isV = VSPLIT && (n0 >= 2560);
  if (isV) {
    #pragma unroll
    for (int m = 0; m < MREP; ++m){
      int grow = m0 + wm*(MREP*16) + m*16 + q*4;       // global row (j=0)
      int bb = grow >> 11, sv = grow & (SEQ-1);
      #pragma unroll
      for (int n = 0; n < 4; ++n){
        int cn = n0 + wn*64 + n*16 + fr - 2560;        // V-local col
        int kvh = cn >> 6, d = cn & 63;
        uint2 w = { cvtpk(acc[m][n][0], acc[m][n][1]), cvtpk(acc[m][n][2], acc[m][n][3]) };
        *(uint2*)(Vt + ((size_t)((bb*8 + kvh)*64 + d))*SEQ + sv) = w;
      }
    }
    return;
  }
  #pragma unroll
  for (int m = 0; m < MREP; ++m){
    #pragma unroll
    for (int n = 0; n < 4; ++n){
      size_t base = (size_t)(m0 + wm*(MREP*16) + m*16 + q*4)*N + (n0 + wn*64 + n*16 + fr);
      #pragma unroll
      for (int j = 0; j < 4; ++j){
        float v = acc[m][n][j];
        if constexpr (sizeof(OUT_T) == 2)
          ((unsigned short*)C)[base + (size_t)j*N] = (unsigned short)f2bf(v);
        else
          ((float*)C)[base + (size_t)j*N] = v;
      }
    }
  }
}

// ---------------- MFMA flash attention: MERGED causal pair, single KV sweep ----------------
// block = 256 thr (4 waves); block = (b, h, pair {31-jj, jj}). The short tile's KV range is a
// SUBSET of the long tile's -> ONE sweep over ntL = qtL+1 tiles updates the LONG chain every
// tile and the SHORT chain while t <= qtS. Same 33 q-tile-updates/block, but staged tiles and
// barrier pairs drop 33 -> 32-jj (avg 24.5, -26%), and K/V LDS fragments are SHARED by both
// chains' MFMAs. Two independent softmax chains interleave on the VALU (T15 mechanism, free).
// Per-chain operation order identical to R15 -> bit-identical numerics.
// LDS: K0 8K | K1 8K | V 8K | P 4 waves x 4K = 40KB (4 blocks/CU).
__global__ __launch_bounds__(256) void k_attn_mfma(const unsigned short* __restrict__ Q,
                                                   const unsigned short* __restrict__ Kb,
                                                   const unsigned short* __restrict__ Vt,
                                                   unsigned short* __restrict__ O,
                                                   const int* __restrict__ maskp,
                                                   const float* __restrict__ ct,
                                                   const float* __restrict__ st){
  __shared__ __align__(16) char smem[40960];   // K0 | K1 | V | P(4x4K: L 2K + S 2K per wave)
  char* Vsm = smem + 16384;
  const int orig = blockIdx.x;
  const int bid = (orig & 7)*128 + (orig >> 3);   // XCD swizzle (1024 blocks, bijective)
  const int jj = bid & 15;
  const int h  = (bid >> 4) & 31;
  const int b  = bid >> 9;
  const int kvh = h >> 2;
  const int tid = threadIdx.x;
  const int wid = tid >> 6, lane = tid & 63;
  const int q_ = lane & 15, g = lane >> 4;
  char* PsmL = smem + 24576 + wid*4096;
  char* PsmS = PsmL + 2048;
  const bool causal = (maskp[0] != 0);

  const int qtL = 31 - jj, qtS = jj;
  const int q0L = qtL*64, q0S = qtS*64;
  const int qgL = q0L + 16*wid + q_;
  const int qgS = q0S + 16*wid + q_;
  const int ntL = causal ? (qtL+1) : (SEQ/64);

  bf16x8 onesf;
  #pragma unroll
  for (int e = 0; e < 8; ++e) onesf[e] = (short)0x3F80;

  auto stageK = [&](int tile, int bufbase){
    const int s0s = tile*64;
    #pragma unroll
    for (int it = 0; it < 2; ++it) {
      int i = (wid*2+it)*64 + lane;
      int s = i >> 3, c = i & 7;
      async_copy16(Kb + (size_t)(b*SEQ + s0s + s)*QKV_N + kvh*HEAD_DIM + ((c ^ (s&7))*8),
                   smem + bufbase + (wid*2+it)*1024);
    }
  };
  auto stageV = [&](int tile){
    const int s0s = tile*64;
    #pragma unroll
    for (int it = 0; it < 2; ++it) {
      int i = (wid*2+it)*64 + lane;
      int s = i >> 3, c = i & 7;
      async_copy16(Vt + ((size_t)(b*N_KV_HEAD + kvh)*HEAD_DIM + s)*SEQ + s0s + ((c ^ (s&7))*8),
                   Vsm + (wid*2+it)*1024);
    }
  };

  // fused Q-RoPE for BOTH q rows (scale folded: scores emerge log2-scaled)
  auto ropeq = [&](int qg, bf16x8& f0, bf16x8& f1){
    const unsigned short* qsrc = Q + (size_t)(b*SEQ + qg)*QKV_N + h*HEAD_DIM + g*16;
    union { bf16x8 h; unsigned u[4]; } xa, xb;
    xa.h = *(const bf16x8*)(qsrc);
    xb.h = *(const bf16x8*)(qsrc + 8);
    const float4* cp = (const float4*)(ct + qg%SEQ*32 + g*8);
    const float4* sp = (const float4*)(st + qg%SEQ*32 + g*8);
    float4 c0 = cp[0], c1 = cp[1];
    float4 s0 = sp[0], s1 = sp[1];
    float cc[8] = {c0.x,c0.y,c0.z,c0.w,c1.x,c1.y,c1.z,c1.w};
    float ss[8] = {s0.x,s0.y,s0.z,s0.w,s1.x,s1.y,s1.z,s1.w};
    float e0[8], e1[8];
    #pragma unroll
    for (int e = 0; e < 8; ++e) {
      unsigned u = (e < 4) ? xa.u[e] : xb.u[e-4];
      float x1 = bflo(u), x2 = bfhi(u);
      float cs = cc[e]*SCL2F, sn = ss[e]*SCL2F;
      e0[e] = x1*cs - x2*sn;
      e1[e] = x1*sn + x2*cs;
    }
    union { unsigned u[4]; bf16x8 h; } p0, p1;
    #pragma unroll
    for (int m = 0; m < 4; ++m) {
      p0.u[m] = cvtpk(e0[2*m], e0[2*m+1]);
      p1.u[m] = cvtpk(e1[2*m], e1[2*m+1]);
    }
    f0 = p0.h; f1 = p1.h;
  };
  bf16x8 qfL0, qfL1, qfS0, qfS1;
  ropeq(qgL, qfL0, qfL1);
  ropeq(qgS, qfS0, qfS1);

  f32x4 accL[4] = {}, accS[4] = {};
  f32x4 acclL = {}, acclS = {};
  float mL = -1e30f, mS = -1e30f;

  stageK(0, 0);
  stageV(0);
  asm volatile("s_waitcnt vmcnt(0)" ::: "memory");
  __syncthreads();

  for (int t = 0; t < ntL; ++t) {
    const int s0 = t*64;
    const int cur = t & 1;
    const char* Kbuf = smem + cur*8192;
    const bool bothA = (!causal) || (t <= qtS);

    if (t+1 < ntL) stageK(t+1, (cur^1)*8192);

    // QK^T both chains, SHARED K fragments
    f32x4 saL[4], saS[4];
    __builtin_amdgcn_s_setprio(1);
    #pragma unroll
    for (int f = 0; f < 4; ++f) {
      const char* kb = Kbuf + (16*f + q_)*128;
      bf16x8 a0 = *(const bf16x8*)(kb + ((g ^ (q_&7))*16));
      bf16x8 a1 = *(const bf16x8*)(kb + (((g+4) ^ (q_&7))*16));
      f32x4 zL = {};
      zL = __builtin_amdgcn_mfma_f32_16x16x32_bf16(a0, qfL0, zL, 0, 0, 0);
      zL = __builtin_amdgcn_mfma_f32_16x16x32_bf16(a1, qfL1, zL, 0, 0, 0);
      saL[f] = zL;
      if (bothA) {
        f32x4 zS = {};
        zS = __builtin_amdgcn_mfma_f32_16x16x32_bf16(a0, qfS0, zS, 0, 0, 0);
        zS = __builtin_amdgcn_mfma_f32_16x16x32_bf16(a1, qfS1, zS, 0, 0, 0);
        saS[f] = zS;
      }
    }
    __builtin_amdgcn_s_setprio(0);

    // -------- softmax chain L --------
    {
      const bool domask = causal && (t == qtL);
      float cm[4];
      #pragma unroll
      for (int f = 0; f < 4; ++f) {
        #pragma unroll
        for (int r = 0; r < 4; ++r) {
          float v = saL[f][r];
          if (domask && (s0 + 16*f + 4*g + r > qgL)) v = -3.0e38f;
          saL[f][r] = v;
        }
        cm[f] = fmaxf(fmaxf(saL[f][0], saL[f][1]), fmaxf(saL[f][2], saL[f][3]));
      }
      float cmax = fmaxf(fmaxf(cm[0], cm[1]), fmaxf(cm[2], cm[3]));
      cmax = fmaxf(cmax, __shfl_xor(cmax, 16));
      cmax = fmaxf(cmax, __shfl_xor(cmax, 32));
      if (!__all(cmax <= mL + 8.0f)) {
        float mnew = fmaxf(mL, cmax);
        float r2 = exp2f(mL - mnew);
        #pragma unroll
        for (int m = 0; m < 4; ++m) {
          accL[m][0] *= r2; accL[m][1] *= r2; accL[m][2] *= r2; accL[m][3] *= r2;
        }
        acclL[0] *= r2; acclL[1] *= r2; acclL[2] *= r2; acclL[3] *= r2;
        mL = mnew;
      }
      #pragma unroll
      for (int f = 0; f < 4; ++f) {
        float e0 = exp2f(saL[f][0] - mL);
        float e1 = exp2f(saL[f][1] - mL);
        float e2 = exp2f(saL[f][2] - mL);
        float e3 = exp2f(saL[f][3] - mL);
        uint2 w = { cvtpk(e0, e1), cvtpk(e2, e3) };
        int byteo = q_*128 + (((2*f + (g>>1)) ^ (q_&7))*16) + (g&1)*8;
        *(uint2*)(PsmL + byteo) = w;
      }
    }
    // -------- softmax chain S (independent; overlaps L on VALU) --------
    if (bothA) {
      const bool domask = causal && (t == qtS);
      float cm[4];
      #pragma unroll
      for (int f = 0; f < 4; ++f) {
        #pragma unroll
        for (int r = 0; r < 4; ++r) {
          float v = saS[f][r];
          if (domask && (s0 + 16*f + 4*g + r > qgS)) v = -3.0e38f;
          saS[f][r] = v;
        }
        cm[f] = fmaxf(fmaxf(saS[f][0], saS[f][1]), fmaxf(saS[f][2], saS[f][3]));
      }
      float cmax = fmaxf(fmaxf(cm[0], cm[1]), fmaxf(cm[2], cm[3]));
      cmax = fmaxf(cmax, __shfl_xor(cmax, 16));
      cmax = fmaxf(cmax, __shfl_xor(cmax, 32));
      if (!__all(cmax <= mS + 8.0f)) {
        float mnew = fmaxf(mS, cmax);
        float r2 = exp2f(mS - mnew);
        #pragma unroll
        for (int m = 0; m < 4; ++m) {
          accS[m][0] *= r2; accS[m][1] *= r2; accS[m][2] *= r2; accS[m][3] *= r2;
        }
        acclS[0] *= r2; acclS[1] *= r2; acclS[2] *= r2; acclS[3] *= r2;
        mS = mnew;
      }
      #pragma unroll
      for (int f = 0; f < 4; ++f) {
        float e0 = exp2f(saS[f][0] - mS);
        float e1 = exp2f(saS[f][1] - mS);
        float e2 = exp2f(saS[f][2] - mS);
        float e3 = exp2f(saS[f][3] - mS);
        uint2 w = { cvtpk(e0, e1), cvtpk(e2, e3) };
        int byteo = q_*128 + (((2*f + (g>>1)) ^ (q_&7))*16) + (g&1)*8;
        *(uint2*)(PsmS + byteo) = w;
      }
    }

    // drain own K(t+1) + own V(t); barrier -> valid block-wide
    asm volatile("s_waitcnt vmcnt(0)" ::: "memory");
    __syncthreads();

    // PV both chains, SHARED V fragments
    __builtin_amdgcn_s_setprio(1);
    #pragma unroll
    for (int kh = 0; kh < 2; ++kh) {
      int po = q_*128 + (((g + 4*kh) ^ (q_&7))*16);
      bf16x8 pbL = *(const bf16x8*)(PsmL + po);
      acclL = __builtin_amdgcn_mfma_f32_16x16x32_bf16(onesf, pbL, acclL, 0, 0, 0);
      bf16x8 pbS;
      if (bothA) {
        pbS = *(const bf16x8*)(PsmS + po);
        acclS = __builtin_amdgcn_mfma_f32_16x16x32_bf16(onesf, pbS, acclS, 0, 0, 0);
      }
      #pragma unroll
      for (int m = 0; m < 4; ++m) {
        bf16x8 va = *(const bf16x8*)(Vsm + (16*m + q_)*128 + (((g + 4*kh) ^ (q_&7))*16));
        accL[m] = __builtin_amdgcn_mfma_f32_16x16x32_bf16(va, pbL, accL[m], 0, 0, 0);
        if (bothA)
          accS[m] = __builtin_amdgcn_mfma_f32_16x16x32_bf16(va, pbS, accS[m], 0, 0, 0);
      }
    }
    __builtin_amdgcn_s_setprio(0);

    __syncthreads();                 // all Vsm readers done -> safe to restage
    if (t+1 < ntL) stageV(t+1);
  }

  // epilogue: both chains; O^T -> wave-private P LDS (swizzled) -> coalesced store
  {
    float inv = 1.0f / acclL[0];
    #pragma unroll
    for (int m = 0; m < 4; ++m) {
      uint2 w = { cvtpk(accL[m][0]*inv, accL[m][1]*inv), cvtpk(accL[m][2]*inv, accL[m][3]*inv) };
      int byteo = q_*128 + (((2*m + (g>>1)) ^ (q_&7))*16) + (g&1)*8;
      *(uint2*)(PsmL + byteo) = w;
    }
    #pragma unroll
    for (int cc = 0; cc < 2; ++cc) {
      int row = lane >> 2;
      int ch = (lane & 3)*2 + cc;
      uint4 v = *(const uint4*)(PsmL + row*128 + ((ch ^ (row&7))*16));
      *(uint4*)(O + (size_t)(b*SEQ + q0L + 16*wid + row)*D_MODEL + h*HEAD_DIM + ch*8) = v;
    }
  }
  {
    float inv = 1.0f / acclS[0];
    #pragma unroll
    for (int m = 0; m < 4; ++m) {
      uint2 w = { cvtpk(accS[m][0]*inv, accS[m][1]*inv), cvtpk(accS[m][2]*inv, accS[m][3]*inv) };
      int byteo = q_*128 + (((2*m + (g>>1)) ^ (q_&7))*16) + (g&1)*8;
      *(uint2*)(PsmS + byteo) = w;
    }
    #pragma unroll
    for (int cc = 0; cc < 2; ++cc) {
      int row = lane >> 2;
      int ch = (lane & 3)*2 + cc;
      uint4 v = *(const uint4*)(PsmS + row*128 + ((ch ^ (row&7))*16));
      *(uint4*)(O + (size_t)(b*SEQ + q0S + 16*wid + row)*D_MODEL + h*HEAD_DIM + ch*8) = v;
    }
  }
}

extern "C" void kernel_launch(void* const* d_in, const int* in_sizes, int n_in,
                              void* d_out, int out_size, void* d_ws, size_t ws_size,
                              hipStream_t stream){
  const float* x  = (const float*)d_in[0];
  const float* Wq = (const float*)d_in[1];
  const float* Wk = (const float*)d_in[2];
  const float* Wv = (const float*)d_in[3];
  const float* Wo = (const float*)d_in[4];
  const int* maskp = (const int*)d_in[5];
  float* out = (float*)d_out;

  char* ws = (char*)d_ws;
  unsigned short* xb    = (unsigned short*)(ws);               // 16 MB [4096][2048]
  unsigned short* AO    = (unsigned short*)(ws);               // 16 MB (xb dead after QKV GEMM)
  unsigned short* Wqkvt = (unsigned short*)(ws + 16777216);    // 12 MB [3072][2048]
  unsigned short* Wot   = (unsigned short*)(ws + 29360128);    //  8 MB [2048][2048]
  unsigned short* QKVb  = (unsigned short*)(ws + 37748736);    // 24 MB [4096][3072]
  float* ct = (float*)(ws + 62914560);                         // 256 KB [2048][32]
  float* st = (float*)(ws + 63176704);                         // 256 KB
  unsigned short* Vt = (unsigned short*)(ws + 63438848);       //  4 MB [16][64][2048]

  // fused prep: cvt (8192) | weight transposes (2560) | rope tables (256)
  k_prep<<<11008, 256, 0, stream>>>(x, Wq, Wk, Wv, Wo, xb, Wqkvt, Wot, ct, st);

  // fused QKV projection, 8-phase 256x256; V-tiles stream transposed into Vt
  k_gemm8<8, true, unsigned short><<<192, 512, 0, stream>>>(xb, Wqkvt, QKVb, Vt, 4096, QKV_N, 2048);

  // RoPE-K in place
  k_ropek<<<128, 256, 0, stream>>>(QKVb, ct, st);

  // merged-pair attention: 1024 uniform blocks, one KV sweep per pair
  k_attn_mfma<<<BATCH*N_HEAD*16, 256, 0, stream>>>(QKVb, QKVb + 2048, Vt, AO, maskp, ct, st);

  // output projection, 8-phase 128x256 (256 blocks, 96K static LDS)
  k_gemm8<4, false, float><<<256, 512, 0, stream>>>(AO, Wot, out, (unsigned short*)nullptr, 4096, 2048, 2048);
}

// Round 19
// 206.985 us; speedup vs baseline: 1.1770x; 1.1770x over previous
//
#include <hip/hip_runtime.h>
#include <stdint.h>

#define D_MODEL 2048
#define N_HEAD 32
#define N_KV_HEAD 8
#define HEAD_DIM 64
#define BATCH 2
#define SEQ 2048
#define ROWS (BATCH*SEQ)   // 4096
#define QKV_N 3072         // fused projection width: Q 0..2047 | K 2048..2559 | V 2560..3071
#define SCL2F 0.18033688011112042f   // 0.125 * log2(e)

typedef __attribute__((ext_vector_type(4))) float f32x4;
typedef __attribute__((ext_vector_type(8))) short bf16x8;

__device__ __forceinline__ float bflo(unsigned u){ return __uint_as_float(u << 16); }
__device__ __forceinline__ float bfhi(unsigned u){ return __uint_as_float(u & 0xFFFF0000u); }
__device__ __forceinline__ unsigned f2bf(float f){
  unsigned u = __float_as_uint(f);
  u += 0x7FFFu + ((u >> 16) & 1u);
  return u >> 16;   // RNE bf16 in low 16 bits
}
__device__ __forceinline__ unsigned cvtpk(float a, float b){
  unsigned r;
  asm("v_cvt_pk_bf16_f32 %0, %1, %2" : "=v"(r) : "v"(a), "v"(b));
  return r;
}

__device__ __forceinline__ void async_copy16(const void* g, void* lds){
  __builtin_amdgcn_global_load_lds(
      (const __attribute__((address_space(1))) void*)g,
      (__attribute__((address_space(3))) void*)lds, 16, 0, 0);
}

// ---------------- fused prep: fp32->bf16 cvt | 4 weight transposes | RoPE tables ----------------
__global__ __launch_bounds__(256) void k_prep(const float* __restrict__ x,
                                              const float* __restrict__ Wq,
                                              const float* __restrict__ Wk,
                                              const float* __restrict__ Wv,
                                              const float* __restrict__ Wo,
                                              unsigned short* __restrict__ xb,
                                              unsigned short* __restrict__ Wqkvt,
                                              unsigned short* __restrict__ Wot,
                                              float* __restrict__ ct,
                                              float* __restrict__ st){
  __shared__ float tile[64][65];
  const int bid = blockIdx.x;
  const int tid = threadIdx.x;
  if (bid < 8192) {
    int i = bid*256 + tid;
    float4 v = ((const float4*)x)[i];
    unsigned lo = f2bf(v.x) | (f2bf(v.y) << 16);
    unsigned hi = f2bf(v.z) | (f2bf(v.w) << 16);
    ((uint2*)xb)[i] = make_uint2(lo, hi);
    return;
  }
  if (bid < 10752) {
    const int rel0 = bid - 8192;
    const float* W; unsigned short* Wt; int N; int rel;
    if (rel0 < 1024)      { W = Wq; Wt = Wqkvt;                         N = 2048; rel = rel0; }
    else if (rel0 < 1280) { W = Wk; Wt = Wqkvt + (size_t)2048*D_MODEL;  N = 512;  rel = rel0 - 1024; }
    else if (rel0 < 1536) { W = Wv; Wt = Wqkvt + (size_t)2560*D_MODEL;  N = 512;  rel = rel0 - 1280; }
    else                  { W = Wo; Wt = Wot;                           N = 2048; rel = rel0 - 1536; }
    const int ntn = N >> 6;
    const int tk = rel / ntn, tn = rel % ntn;
    #pragma unroll
    for (int i = 0; i < 4; ++i) {
      int idx4 = tid + 256*i;
      int r = idx4 >> 4;
      int c4 = idx4 & 15;
      float4 v = *(const float4*)(W + (size_t)(tk*64 + r)*N + tn*64 + c4*4);
      tile[r][c4*4+0] = v.x; tile[r][c4*4+1] = v.y;
      tile[r][c4*4+2] = v.z; tile[r][c4*4+3] = v.w;
    }
    __syncthreads();
    #pragma unroll
    for (int i = 0; i < 8; ++i) {
      int o2 = tid + 256*i;
      int n  = o2 >> 5;
      int k2 = o2 & 31;
      unsigned lo = f2bf(tile[k2*2+0][n]);
      unsigned hi = f2bf(tile[k2*2+1][n]);
      *(unsigned*)(Wt + (size_t)(tn*64 + n)*D_MODEL + tk*64 + k2*2) = lo | (hi << 16);
    }
    return;
  }
  {
    int gid = (bid - 10752)*256 + tid;   // SEQ*32
    int t = gid >> 5, d = gid & 31;
    float inv = exp2f(-13.287712379549449f * ((float)d * (1.0f/32.0f)));
    float a = (float)t * inv;
    ct[gid] = cosf(a);
    st[gid] = sinf(a);
  }
}

// ---------------- RoPE-K in-place (128 blocks); V handled by the GEMM epilogue ----------------
__global__ __launch_bounds__(256) void k_ropek(unsigned short* __restrict__ QKVb,
                                               const float* __restrict__ ct,
                                               const float* __restrict__ st){
  int gid = blockIdx.x*256 + threadIdx.x;   // ROWS*N_KV_HEAD
  int row = gid >> 3;
  int h = gid & 7;
  int t = row & (SEQ-1);
  unsigned* p = (unsigned*)(QKVb + (size_t)row*QKV_N + 2048 + h*HEAD_DIM);
  float o1[32], o2[32];
  #pragma unroll
  for (int d = 0; d < 32; ++d) {
    unsigned u = p[d];
    float x1 = bflo(u), x2 = bfhi(u);
    float c = ct[t*32+d], s = st[t*32+d];
    o1[d] = x1*c - x2*s;
    o2[d] = x1*s + x2*c;
  }
  #pragma unroll
  for (int i = 0; i < 16; ++i) {
    p[i]    = f2bf(o1[2*i]) | (f2bf(o1[2*i+1]) << 16);
    p[16+i] = f2bf(o2[2*i]) | (f2bf(o2[2*i+1]) << 16);
  }
}

// ---------------- 8-phase pipelined bf16 GEMM (T2+T3+T4+T5): C = A[M][K] * Bt[N][K]^T ----------------
// R15-proven schedule. VSPLIT: N-tiles with n0 >= 2560 (pure V in the fused QKV projection)
// write their output TRANSPOSED directly into Vt[(b*8+kvh)*64+d][s].
template<int MREP, bool VSPLIT, typename OUT_T>
__global__ __launch_bounds__(512, 1) void k_gemm8(const unsigned short* __restrict__ A,
                                                  const unsigned short* __restrict__ Bt,
                                                  OUT_T* __restrict__ C,
                                                  unsigned short* __restrict__ Vt,
                                                  int M, int N, int K){
  constexpr int BM = MREP*32;
  constexpr int ABYTES = BM*128;
  constexpr int AHALF  = BM*64;
  constexpr int BUF = ABYTES + 32768;
  constexpr int LA = MREP/4;
  constexpr int VMW = 6 + 2*LA;

  __shared__ __align__(16) char smem[2*BUF];

  const int nbn = N >> 8;
  const int bswz = ((int)blockIdx.x & 7)*((int)gridDim.x >> 3) + ((int)blockIdx.x >> 3);
  const int m0 = (bswz / nbn) * BM;
  const int n0 = (bswz % nbn) * 256;
  const int tid = threadIdx.x;
  const int wid = tid >> 6, lane = tid & 63;
  const int wm = wid >> 2, wn = wid & 3;
  const int fr = lane & 15, q = lane >> 4;
  const int NT = K >> 6;
  const int NITER = NT >> 1;
  const size_t rb = (size_t)K*2;

  f32x4 acc[MREP][4] = {};
  bf16x8 Bfrag[4];

  const int srow = tid >> 2, sq = tid & 3;

  auto stageA = [&](int t, int ks, int bufb){
    #pragma unroll
    for (int r = 0; r < LA; ++r){
      int row = r*128 + srow;
      int sw = ((row >> 1) & 3);
      async_copy16((const char*)A + (size_t)(m0+row)*rb + t*128 + ks*64 + ((sq ^ sw)*16),
                   smem + bufb + ks*AHALF + (r*512 + tid)*16);
    }
  };
  auto stageB = [&](int t, int ks, int bufb){
    #pragma unroll
    for (int r = 0; r < 2; ++r){
      int row = r*128 + srow;
      int sw = ((row >> 1) & 3);
      async_copy16((const char*)Bt + (size_t)(n0+row)*rb + t*128 + ks*64 + ((sq ^ sw)*16),
                   smem + bufb + ABYTES + ks*16384 + (r*512 + tid)*16);
    }
  };

#define PHASE(KS, MH, BUFB, LOADB, STAGE_STMT, DO_VMCNT) {                              \
    bf16x8 Af[MREP/2];                                                                  \
    _Pragma("unroll")                                                                   \
    for (int mm = 0; mm < MREP/2; ++mm){                                                \
      int row = wm*(MREP*16) + ((MH)*(MREP/2)+mm)*16 + fr;                              \
      Af[mm] = *(const bf16x8*)(smem + (BUFB) + (KS)*AHALF + row*64 +                   \
                                ((q ^ ((row>>1)&3))*16));                               \
    }                                                                                   \
    if (LOADB){                                                                         \
      _Pragma("unroll")                                                                 \
      for (int n = 0; n < 4; ++n){                                                      \
        int row = wn*64 + n*16 + fr;                                                    \
        Bfrag[n] = *(const bf16x8*)(smem + (BUFB) + ABYTES + (KS)*16384 + row*64 +      \
                                    ((q ^ ((row>>1)&3))*16));                           \
      }                                                                                 \
    }                                                                                   \
    STAGE_STMT;                                                                         \
    __builtin_amdgcn_s_barrier();                                                       \
    __builtin_amdgcn_s_setprio(1);                                                      \
    _Pragma("unroll")                                                                   \
    for (int mm = 0; mm < MREP/2; ++mm)                                                 \
      _Pragma("unroll")                                                                 \
      for (int n = 0; n < 4; ++n)                                                       \
        acc[(MH)*(MREP/2)+mm][n] = __builtin_amdgcn_mfma_f32_16x16x32_bf16(             \
            Af[mm], Bfrag[n], acc[(MH)*(MREP/2)+mm][n], 0, 0, 0);                       \
    __builtin_amdgcn_s_setprio(0);                                                      \
    if (DO_VMCNT) asm volatile("s_waitcnt vmcnt(%0)" :: "n"(VMW) : "memory");           \
    __builtin_amdgcn_s_barrier();                                                       \
  }

  stageB(0, 0, 0);  stageA(0, 0, 0);  stageB(0, 1, 0);  stageA(0, 1, 0);
  stageB(1, 0, BUF); stageA(1, 0, BUF); stageB(1, 1, BUF);
  asm volatile("s_waitcnt vmcnt(%0)" :: "n"(VMW) : "memory");
  __builtin_amdgcn_s_barrier();

  for (int i = 0; i < NITER; ++i){
    const int t2 = (2*i+2) & (NT-1);
    const int t3 = (2*i+3) & (NT-1);
    PHASE(0, 0, 0,   true,  stageA(2*i+1, 1, BUF), false)
    PHASE(0, 1, 0,   false, stageB(t2, 0, 0),      true)
    PHASE(1, 0, 0,   true,  stageA(t2, 0, 0),      false)
    PHASE(1, 1, 0,   false, stageB(t2, 1, 0),      true)
    PHASE(0, 0, BUF, true,  stageA(t2, 1, 0),      false)
    PHASE(0, 1, BUF, false, stageB(t3, 0, BUF),    true)
    PHASE(1, 0, BUF, true,  stageA(t3, 0, BUF),    false)
    PHASE(1, 1, BUF, false, stageB(t3, 1, BUF),    true)
  }
#undef PHASE

  asm volatile("s_waitcnt vmcnt(0)" ::: "memory");
  const bool isV = VSPLIT && (n0 >= 2560);
  if (isV) {
    #pragma unroll
    for (int m = 0; m < MREP; ++m){
      int grow = m0 + wm*(MREP*16) + m*16 + q*4;       // global row (j=0)
      int bb = grow >> 11, sv = grow & (SEQ-1);
      #pragma unroll
      for (int n = 0; n < 4; ++n){
        int cn = n0 + wn*64 + n*16 + fr - 2560;        // V-local col
        int kvh = cn >> 6, d = cn & 63;
        uint2 w = { cvtpk(acc[m][n][0], acc[m][n][1]), cvtpk(acc[m][n][2], acc[m][n][3]) };
        *(uint2*)(Vt + ((size_t)((bb*8 + kvh)*64 + d))*SEQ + sv) = w;
      }
    }
    return;
  }
  #pragma unroll
  for (int m = 0; m < MREP; ++m){
    #pragma unroll
    for (int n = 0; n < 4; ++n){
      size_t base = (size_t)(m0 + wm*(MREP*16) + m*16 + q*4)*N + (n0 + wn*64 + n*16 + fr);
      #pragma unroll
      for (int j = 0; j < 4; ++j){
        float v = acc[m][n][j];
        if constexpr (sizeof(OUT_T) == 2)
          ((unsigned short*)C)[base + (size_t)j*N] = (unsigned short)f2bf(v);
        else
          ((float*)C)[base + (size_t)j*N] = v;
      }
    }
  }
}

// ---------------- MFMA flash attention (R15-best: ones-MFMA denom + fused Q-RoPE) ----------------
// block = 256 thr (4 waves); block = (b, h, q-tile PAIR {31-j, j}) -> uniform 33 tiles/block.
// LDS: K dbuf 2x8K | V 8K | P 4x2K = 32KB. Measured 102.8-103.3 us.
__global__ __launch_bounds__(256) void k_attn_mfma(const unsigned short* __restrict__ Q,
                                                   const unsigned short* __restrict__ Kb,
                                                   const unsigned short* __restrict__ Vt,
                                                   unsigned short* __restrict__ O,
                                                   const int* __restrict__ maskp,
                                                   const float* __restrict__ ct,
                                                   const float* __restrict__ st){
  __shared__ __align__(16) char smem[32768];   // K0 8K | K1 8K | V 8K | P 4x2K
  char* Vsm = smem + 16384;
  const int orig = blockIdx.x;
  const int bid = (orig & 7)*128 + (orig >> 3);
  const int jj = bid & 15;
  const int h  = (bid >> 4) & 31;
  const int b  = bid >> 9;
  const int kvh = h >> 2;
  const int tid = threadIdx.x;
  const int wid = tid >> 6, lane = tid & 63;
  const int q_ = lane & 15, g = lane >> 4;
  char* Psm = smem + 24576 + wid*2048;
  const bool causal = (maskp[0] != 0);

  bf16x8 onesf;
  #pragma unroll
  for (int e = 0; e < 8; ++e) onesf[e] = (short)0x3F80;

  auto stageK = [&](int tile, int bufbase){
    const int s0s = tile*64;
    #pragma unroll
    for (int it = 0; it < 2; ++it) {
      int i = (wid*2+it)*64 + lane;
      int s = i >> 3, c = i & 7;
      async_copy16(Kb + (size_t)(b*SEQ + s0s + s)*QKV_N + kvh*HEAD_DIM + ((c ^ (s&7))*8),
                   smem + bufbase + (wid*2+it)*1024);
    }
  };
  auto stageV = [&](int tile){
    const int s0s = tile*64;
    #pragma unroll
    for (int it = 0; it < 2; ++it) {
      int i = (wid*2+it)*64 + lane;
      int s = i >> 3, c = i & 7;
      async_copy16(Vt + ((size_t)(b*N_KV_HEAD + kvh)*HEAD_DIM + s)*SEQ + s0s + ((c ^ (s&7))*8),
                   Vsm + (wid*2+it)*1024);
    }
  };

  for (int pass = 0; pass < 2; ++pass) {
    const int qt = pass ? jj : (31 - jj);
    const int q0 = qt*64;
    const int qg = q0 + 16*wid + q_;
    const int nt = causal ? (qt+1) : (SEQ/64);

    bf16x8 qf0, qf1;
    {
      const int trow = qg;
      const unsigned short* qsrc = Q + (size_t)(b*SEQ + trow)*QKV_N + h*HEAD_DIM + g*16;
      union { bf16x8 h; unsigned u[4]; } xa, xb;
      xa.h = *(const bf16x8*)(qsrc);
      xb.h = *(const bf16x8*)(qsrc + 8);
      const float4* cp = (const float4*)(ct + trow*32 + g*8);
      const float4* sp = (const float4*)(st + trow*32 + g*8);
      float4 c0 = cp[0], c1 = cp[1];
      float4 s0 = sp[0], s1 = sp[1];
      float cc[8] = {c0.x,c0.y,c0.z,c0.w,c1.x,c1.y,c1.z,c1.w};
      float ss[8] = {s0.x,s0.y,s0.z,s0.w,s1.x,s1.y,s1.z,s1.w};
      float e0[8], e1[8];
      #pragma unroll
      for (int e = 0; e < 8; ++e) {
        unsigned u = (e < 4) ? xa.u[e] : xb.u[e-4];
        float x1 = bflo(u), x2 = bfhi(u);
        float cs = cc[e]*SCL2F, sn = ss[e]*SCL2F;
        e0[e] = x1*cs - x2*sn;
        e1[e] = x1*sn + x2*cs;
      }
      union { unsigned u[4]; bf16x8 h; } p0, p1;
      #pragma unroll
      for (int m = 0; m < 4; ++m) {
        p0.u[m] = cvtpk(e0[2*m], e0[2*m+1]);
        p1.u[m] = cvtpk(e1[2*m], e1[2*m+1]);
      }
      qf0 = p0.h; qf1 = p1.h;
    }

    f32x4 acc[4] = {};
    f32x4 accl = {};
    float mrun = -1e30f;

    stageK(0, 0);
    stageV(0);
    asm volatile("s_waitcnt vmcnt(0)" ::: "memory");
    __syncthreads();

    for (int t = 0; t < nt; ++t) {
      const int s0 = t*64;
      const int cur = t & 1;
      const char* Kbuf = smem + cur*8192;

      if (t+1 < nt) stageK(t+1, (cur^1)*8192);

      f32x4 sa[4];
      __builtin_amdgcn_s_setprio(1);
      #pragma unroll
      for (int f = 0; f < 4; ++f) {
        const char* kb = Kbuf + (16*f + q_)*128;
        bf16x8 a0 = *(const bf16x8*)(kb + ((g ^ (q_&7))*16));
        bf16x8 a1 = *(const bf16x8*)(kb + (((g+4) ^ (q_&7))*16));
        f32x4 z = {};
        z = __builtin_amdgcn_mfma_f32_16x16x32_bf16(a0, qf0, z, 0, 0, 0);
        z = __builtin_amdgcn_mfma_f32_16x16x32_bf16(a1, qf1, z, 0, 0, 0);
        sa[f] = z;
      }
      __builtin_amdgcn_s_setprio(0);

      const bool domask = causal && (t == qt);
      float x[4][4];
      float cm[4];
      #pragma unroll
      for (int f = 0; f < 4; ++f) {
        #pragma unroll
        for (int r = 0; r < 4; ++r) {
          float v = sa[f][r];
          if (domask && (s0 + 16*f + 4*g + r > qg)) v = -3.0e38f;
          x[f][r] = v;
        }
        cm[f] = fmaxf(fmaxf(x[f][0], x[f][1]), fmaxf(x[f][2], x[f][3]));
      }
      float cmax = fmaxf(fmaxf(cm[0], cm[1]), fmaxf(cm[2], cm[3]));
      cmax = fmaxf(cmax, __shfl_xor(cmax, 16));
      cmax = fmaxf(cmax, __shfl_xor(cmax, 32));
      if (!__all(cmax <= mrun + 8.0f)) {
        float mnew = fmaxf(mrun, cmax);
        float r2 = exp2f(mrun - mnew);
        #pragma unroll
        for (int m = 0; m < 4; ++m) {
          acc[m][0] *= r2; acc[m][1] *= r2; acc[m][2] *= r2; acc[m][3] *= r2;
        }
        accl[0] *= r2; accl[1] *= r2; accl[2] *= r2; accl[3] *= r2;
        mrun = mnew;
      }
      #pragma unroll
      for (int f = 0; f < 4; ++f) {
        float e0 = exp2f(x[f][0] - mrun);
        float e1 = exp2f(x[f][1] - mrun);
        float e2 = exp2f(x[f][2] - mrun);
        float e3 = exp2f(x[f][3] - mrun);
        uint2 w = { cvtpk(e0, e1), cvtpk(e2, e3) };
        int byteo = q_*128 + (((2*f + (g>>1)) ^ (q_&7))*16) + (g&1)*8;
        *(uint2*)(Psm + byteo) = w;
      }

      asm volatile("s_waitcnt vmcnt(0)" ::: "memory");
      __syncthreads();

      __builtin_amdgcn_s_setprio(1);
      #pragma unroll
      for (int kh = 0; kh < 2; ++kh) {
        bf16x8 pb = *(const bf16x8*)(Psm + q_*128 + (((g + 4*kh) ^ (q_&7))*16));
        accl = __builtin_amdgcn_mfma_f32_16x16x32_bf16(onesf, pb, accl, 0, 0, 0);
        #pragma unroll
        for (int m = 0; m < 4; ++m) {
          bf16x8 va = *(const bf16x8*)(Vsm + (16*m + q_)*128 + (((g + 4*kh) ^ (q_&7))*16));
          acc[m] = __builtin_amdgcn_mfma_f32_16x16x32_bf16(va, pb, acc[m], 0, 0, 0);
        }
      }
      __builtin_amdgcn_s_setprio(0);

      __syncthreads();
      if (t+1 < nt) stageV(t+1);
    }

    float inv = 1.0f / accl[0];
    #pragma unroll
    for (int m = 0; m < 4; ++m) {
      uint2 w = { cvtpk(acc[m][0]*inv, acc[m][1]*inv), cvtpk(acc[m][2]*inv, acc[m][3]*inv) };
      int byteo = q_*128 + (((2*m + (g>>1)) ^ (q_&7))*16) + (g&1)*8;
      *(uint2*)(Psm + byteo) = w;
    }
    #pragma unroll
    for (int cc = 0; cc < 2; ++cc) {
      int row = lane >> 2;
      int ch = (lane & 3)*2 + cc;
      uint4 v = *(const uint4*)(Psm + row*128 + ((ch ^ (row&7))*16));
      *(uint4*)(O + (size_t)(b*SEQ + q0 + 16*wid + row)*D_MODEL + h*HEAD_DIM + ch*8) = v;
    }
  }
}

extern "C" void kernel_launch(void* const* d_in, const int* in_sizes, int n_in,
                              void* d_out, int out_size, void* d_ws, size_t ws_size,
                              hipStream_t stream){
  const float* x  = (const float*)d_in[0];
  const float* Wq = (const float*)d_in[1];
  const float* Wk = (const float*)d_in[2];
  const float* Wv = (const float*)d_in[3];
  const float* Wo = (const float*)d_in[4];
  const int* maskp = (const int*)d_in[5];
  float* out = (float*)d_out;

  char* ws = (char*)d_ws;
  unsigned short* xb    = (unsigned short*)(ws);               // 16 MB [4096][2048]
  unsigned short* AO    = (unsigned short*)(ws);               // 16 MB (xb dead after QKV GEMM)
  unsigned short* Wqkvt = (unsigned short*)(ws + 16777216);    // 12 MB [3072][2048]
  unsigned short* Wot   = (unsigned short*)(ws + 29360128);    //  8 MB [2048][2048]
  unsigned short* QKVb  = (unsigned short*)(ws + 37748736);    // 24 MB [4096][3072]
  float* ct = (float*)(ws + 62914560);                         // 256 KB [2048][32]
  float* st = (float*)(ws + 63176704);                         // 256 KB
  unsigned short* Vt = (unsigned short*)(ws + 63438848);       //  4 MB [16][64][2048]

  // fused prep: cvt (8192) | weight transposes (2560) | rope tables (256)
  k_prep<<<11008, 256, 0, stream>>>(x, Wq, Wk, Wv, Wo, xb, Wqkvt, Wot, ct, st);

  // fused QKV projection, 8-phase 256x256; V-tiles stream transposed into Vt
  k_gemm8<8, true, unsigned short><<<192, 512, 0, stream>>>(xb, Wqkvt, QKVb, Vt, 4096, QKV_N, 2048);

  // RoPE-K in place
  k_ropek<<<128, 256, 0, stream>>>(QKVb, ct, st);

  // causal-pair-balanced grid: (b, h, pair j) -> 1024 uniform blocks
  k_attn_mfma<<<BATCH*N_HEAD*16, 256, 0, stream>>>(QKVb, QKVb + 2048, Vt, AO, maskp, ct, st);

  // output projection, 8-phase 128x256 (256 blocks, 96K static LDS)
  k_gemm8<4, false, float><<<256, 512, 0, stream>>>(AO, Wot, out, (unsigned short*)nullptr, 4096, 2048, 2048);
}